// Round 4
// baseline (478.835 us; speedup 1.0000x reference)
//
#include <hip/hip_runtime.h>
#include <math.h>

#define Nrows 16384          // B*H*W
#define NE 8192
#define Kdim 256
#define HWsz 1024
#define NSPL 4               // code-group splits (cg)
#define BETAF 0.25f

typedef __attribute__((ext_vector_type(8))) short bf16x8;
typedef __attribute__((ext_vector_type(16))) float f32x16;
typedef unsigned short u16;

__device__ inline u16 bf16_rne(float x) {
  unsigned int u = __float_as_uint(x);
  return (u16)((u + 0x7FFFu + ((u >> 16) & 1u)) >> 16);
}
__device__ inline float bf16_tof(u16 h) {
  return __uint_as_float(((unsigned int)h) << 16);
}
__device__ inline void gll16(const void* g, void* l) {
  __builtin_amdgcn_global_load_lds(
      (const __attribute__((address_space(1))) unsigned int*)g,
      (__attribute__((address_space(3))) unsigned int*)l, 16, 0, 0);
}

// ---- cc[j] = sum_k codebook[j][k]^2 (bit-identical to r1-r9) --------------
__global__ __launch_bounds__(256) void cc_kernel(const float* __restrict__ cb,
                                                 float* __restrict__ cc) {
  int wave = threadIdx.x >> 6;
  int lane = threadIdx.x & 63;
  int row = blockIdx.x * 4 + wave;
  const float4 v = *(const float4*)(cb + (size_t)row * Kdim + lane * 4);
  float s = v.x * v.x + v.y * v.y + v.z * v.z + v.w * v.w;
  for (int off = 32; off; off >>= 1) s += __shfl_down(s, off);
  if (lane == 0) cc[row] = s;
}

// ---- codebook -> frag-order bf16 splits Cf (unchanged r4-r9) --------------
// Group (j32, arr, k16) of 512 u16 at ((j32*3+arr)*16 + k16)*512;
// within group: (khalf*32 + j%32)*8 + i.
__global__ __launch_bounds__(256) void conv_cb(const float* __restrict__ cb,
                                               u16* __restrict__ Cf) {
  const int g = blockIdx.x * 256 + threadIdx.x;   // 0 .. 8192*16-1
  const int j = g >> 4, k16 = g & 15;
  const float* src = cb + (size_t)j * Kdim + k16 * 16;
  float f[16];
#pragma unroll
  for (int q = 0; q < 4; ++q) {
    const float4 v = ((const float4*)src)[q];
    f[q * 4 + 0] = v.x; f[q * 4 + 1] = v.y; f[q * 4 + 2] = v.z; f[q * 4 + 3] = v.w;
  }
  u16 h[3][16];
#pragma unroll
  for (int i = 0; i < 16; ++i) {
    const u16 q0 = bf16_rne(f[i]);
    const float r1 = f[i] - bf16_tof(q0);
    const u16 q1 = bf16_rne(r1);
    const float r2 = r1 - bf16_tof(q1);
    h[0][i] = q0; h[1][i] = q1; h[2][i] = bf16_rne(r2);
  }
  const int j32 = j >> 5, li = j & 31;
#pragma unroll
  for (int arr = 0; arr < 3; ++arr) {
#pragma unroll
    for (int kh = 0; kh < 2; ++kh) {
      const size_t off = ((size_t)(j32 * 3 + arr) * 16 + k16) * 512 + (kh * 32 + li) * 8;
      *(int4*)(Cf + off) = *(int4*)&h[arr][kh * 8];
    }
  }
}

// ---- z (B,C,H,W) -> frag-order bf16 splits Zf + zz (unchanged r4-r9) ------
__global__ __launch_bounds__(256) void conv_z(const float* __restrict__ z,
                                              u16* __restrict__ Zf,
                                              float* __restrict__ zz) {
  __shared__ float tile[64][68];
  const int t = threadIdx.x;
  const int bid = blockIdx.x;
  const int n0 = bid * 64;
  const int b = bid >> 4;
  const int hw0 = (bid & 15) << 6;
  const float* zb = z + (size_t)b * (Kdim * HWsz) + hw0;
  float zzacc = 0.f;
  const int rr = t >> 2;
  const int kq = (t & 3) * 16;
  for (int kc = 0; kc < 4; ++kc) {
#pragma unroll
    for (int i = 0; i < 16; ++i) {
      const int idx = i * 256 + t;
      const int k = idx >> 6, r = idx & 63;
      tile[r][k] = zb[(size_t)(kc * 64 + k) * HWsz + r];
    }
    __syncthreads();
    if (t < 64) {
      for (int k = 0; k < 64; ++k) {
        const float a = tile[t][k];
        zzacc = fmaf(a, a, zzacc);
      }
    }
    u16 h[3][16];
#pragma unroll
    for (int i = 0; i < 16; ++i) {
      const float fv = tile[rr][kq + i];
      const u16 q0 = bf16_rne(fv);
      const float r1 = fv - bf16_tof(q0);
      const u16 q1 = bf16_rne(r1);
      const float r2 = r1 - bf16_tof(q1);
      h[0][i] = q0; h[1][i] = q1; h[2][i] = bf16_rne(r2);
    }
    const int k16 = kc * 4 + (t & 3);
    const int n32 = bid * 2 + (rr >> 5), li = rr & 31;
#pragma unroll
    for (int arr = 0; arr < 3; ++arr) {
#pragma unroll
      for (int kh = 0; kh < 2; ++kh) {
        const size_t off = ((size_t)(n32 * 3 + arr) * 16 + k16) * 512 + (kh * 32 + li) * 8;
        *(int4*)(Zf + off) = *(int4*)&h[arr][kh * 8];
      }
    }
    __syncthreads();
  }
  if (t < 64) zz[n0 + t] = zzacc;
}

// ---- main GEMM+argmin: z-rows persistent in VGPRs, codebook via LDS -------
// r10 = r9 (3-slot rotation, stage lag 2, counted vmcnt(6), raw s_barrier,
// 24 KB chunks, 4 barriers/group) + EXACTLY ONE change: T5 s_setprio(1)
// around each CHUNK's MFMA cluster. Rationale: r9 built the counted-vmcnt
// phase structure T5 requires (catalog: +21-39% on such structures, null
// on lockstep single-phase); role diversity comes from the 2 co-resident
// blocks/CU sitting at different barrier phases — setprio tells the CU
// scheduler to prefer the MFMA-phase wave over the staging-phase wave.
// No numerics impact: MFMA order per accumulator unchanged -> bit-identical.
// LDS 3x24KB + 8KB ccs = 80 KB -> 2 blocks/CU (unchanged).
__global__ __launch_bounds__(256, 2) void vq_gemm(
    const u16* __restrict__ Cf, const u16* __restrict__ Zf,
    const float* __restrict__ cc, const float* __restrict__ zz,
    float* __restrict__ pd, int* __restrict__ pj) {
  __shared__ __align__(16) u16 Al[3][12288];   // 3 x 24 KB rotating slots
  __shared__ float ccs[2048];                  // 80 KB total

  const int t = threadIdx.x;
  const int lane = t & 63;
  const int w = __builtin_amdgcn_readfirstlane(t >> 6);   // 0..3
  const int bid = blockIdx.x;
  const int cg = bid & 3;          // code slice (2048 codes), XCD-pinned
  const int rt = bid >> 2;         // row tile (128 rows)
  const int n32 = rt * 4 + w;      // this wave's 32-row group

#pragma unroll
  for (int i = 0; i < 8; ++i) ccs[i * 256 + t] = cc[cg * 2048 + i * 256 + t];

  const float zzv = zz[n32 * 32 + (lane & 31)];

  // B (z-rows) persistent: 16 kc x 3 limbs x bf16x8 = 192 VGPRs
  bf16x8 B[16][3];
#pragma unroll
  for (int kc = 0; kc < 16; ++kc)
#pragma unroll
    for (int arr = 0; arr < 3; ++arr)
      B[kc][arr] = *(const bf16x8*)(
          Zf + ((size_t)(n32 * 3 + arr) * 16 + kc) * 512 + lane * 8);

// stage chunk (gg, c_) of 64-code group gg into LDS slot sl: 24 cells of
// 1 KB, 6 per wave; dest = wave-uniform cell base + lane*16 (gll16 rule).
// Tail over-issue clamps gg to 0 (valid, L2-hot, lands in a dead slot).
#define STAGE(gg, c_, sl)                                                     \
  {                                                                           \
    const int ggc_ = (gg) < 32 ? (gg) : 0;                                    \
    _Pragma("unroll")                                                         \
    for (int i = 0; i < 6; ++i) {                                             \
      const int s = w * 6 + i;                                                \
      const int jx = s / 12, rem = s % 12;                                    \
      const int kc2 = rem / 3, arr = rem % 3;                                 \
      gll16(Cf + ((size_t)((cg * 64 + ggc_ * 2 + jx) * 3 + arr) * 16 +        \
                  ((c_) * 4 + kc2)) * 512 + lane * 8,                         \
            &Al[sl][((jx * 4 + kc2) * 3 + arr) * 512]);                       \
    }                                                                         \
  }

// per kc: 6 A-frag b128 reads feed 12 MFMAs; per-acc-element product order
// (a0b0,a0b1,a1b0,a1b1,a0b2,a2b0) ascending kc — bit-identical to r3-r9.
#define MF(af, bv, ac) ac = __builtin_amdgcn_mfma_f32_32x32x16_bf16(af, bv, ac, 0, 0, 0);
#define CHUNK(sl, c_)                                                         \
  __builtin_amdgcn_s_setprio(1);                                              \
  _Pragma("unroll")                                                           \
  for (int kc2 = 0; kc2 < 4; ++kc2) {                                         \
    bf16x8 a0[3], a1[3];                                                      \
    _Pragma("unroll")                                                         \
    for (int arr = 0; arr < 3; ++arr) {                                       \
      a0[arr] = *(const bf16x8*)&Al[sl][(kc2 * 3 + arr) * 512 + lane * 8];    \
      a1[arr] = *(const bf16x8*)&Al[sl][((4 + kc2) * 3 + arr) * 512 + lane * 8]; \
    }                                                                         \
    MF(a0[0], B[(c_) * 4 + kc2][0], acc0) MF(a1[0], B[(c_) * 4 + kc2][0], acc1) \
    MF(a0[0], B[(c_) * 4 + kc2][1], acc0) MF(a1[0], B[(c_) * 4 + kc2][1], acc1) \
    MF(a0[1], B[(c_) * 4 + kc2][0], acc0) MF(a1[1], B[(c_) * 4 + kc2][0], acc1) \
    MF(a0[1], B[(c_) * 4 + kc2][1], acc0) MF(a1[1], B[(c_) * 4 + kc2][1], acc1) \
    MF(a0[0], B[(c_) * 4 + kc2][2], acc0) MF(a1[0], B[(c_) * 4 + kc2][2], acc1) \
    MF(a0[2], B[(c_) * 4 + kc2][0], acc0) MF(a1[2], B[(c_) * 4 + kc2][0], acc1) \
  }                                                                           \
  __builtin_amdgcn_s_setprio(0);

// counted wait + raw barrier: certifies the chunk about to be read (all
// waves), never drains the two younger in-flight stages. sched_barrier(0)
// fences stop compile-time motion of ds_reads/MFMAs across it (rule #18).
#define WTB()                                                                 \
  __builtin_amdgcn_sched_barrier(0);                                          \
  asm volatile("s_waitcnt vmcnt(6)" ::: "memory");                            \
  __builtin_amdgcn_s_barrier();                                               \
  __builtin_amdgcn_sched_barrier(0);

#define ROT() { sl = (sl == 2) ? 0 : sl + 1; s2 = (s2 == 2) ? 0 : s2 + 1; }

  // prologue: stage phases 0 and 1 into slots 0 and 1
  STAGE(0, 0, 0)
  STAGE(0, 1, 1)
  // publish ccs ds_writes before the first raw barrier (raw s_barrier does
  // not drain lgkmcnt the way __syncthreads did)
  asm volatile("s_waitcnt lgkmcnt(0)" ::: "memory");
  __builtin_amdgcn_sched_barrier(0);

  float bd = INFINITY;
  int bj = 0;
  const f32x16 zero16 = {0,0,0,0,0,0,0,0,0,0,0,0,0,0,0,0};
  int sl = 0, s2 = 2;   // slot of current phase / of phase+2 (uniform)

  for (int g = 0; g < 32; ++g) {
    f32x16 acc0 = zero16, acc1 = zero16;
    // 4 phases per group; stage runs 2 phases ahead: (g,2),(g,3),(g+1,0),(g+1,1)
    WTB() STAGE(g, 2, s2)     CHUNK(sl, 0) ROT()
    WTB() STAGE(g, 3, s2)     CHUNK(sl, 1) ROT()
    WTB() STAGE(g + 1, 0, s2) CHUNK(sl, 2) ROT()
    WTB() STAGE(g + 1, 1, s2) CHUNK(sl, 3) ROT()

    // epilogue: d = (zz + cc) - 2*acc, ascending j (same expression r1-r9);
    // overlaps the two in-flight stages of the next group.
#pragma unroll
    for (int jx = 0; jx < 2; ++jx) {
      const f32x16& a = jx ? acc1 : acc0;
#pragma unroll
      for (int q = 0; q < 4; ++q) {
        const float4 c4 = *(const float4*)&ccs[g * 64 + jx * 32 + q * 8 + (lane >> 5) * 4];
        const float cv[4] = {c4.x, c4.y, c4.z, c4.w};
#pragma unroll
        for (int r = 0; r < 4; ++r) {
          const float d = (zzv + cv[r]) - 2.0f * a[q * 4 + r];
          const int j = cg * 2048 + g * 64 + jx * 32 + r + q * 8 + (lane >> 5) * 4;
          if (d < bd) { bd = d; bj = j; }
        }
      }
    }
  }
  // drain clamped tail stages: no gll16 LDS-write may be pending at
  // s_endpgm (LDS is reallocated to the next workgroup).
  asm volatile("s_waitcnt vmcnt(0)" ::: "memory");
#undef STAGE
#undef CHUNK
#undef MF
#undef WTB
#undef ROT

  // combine lane halves (same z-row, complementary code sub-columns)
  {
    const float od = __shfl_xor(bd, 32);
    const int oj = __shfl_xor(bj, 32);
    if (od < bd || (od == bd && oj < bj)) { bd = od; bj = oj; }
  }
  if (lane < 32) {
    const int n = n32 * 32 + lane;
    pd[(size_t)cg * Nrows + n] = bd;
    pj[(size_t)cg * Nrows + n] = bj;
  }
}

// ---- combine NSPL code-group partials -> idx, counts ----------------------
__global__ __launch_bounds__(256) void vq_combine(const float* __restrict__ pd,
                                                  const int* __restrict__ pj,
                                                  int* __restrict__ idx_int,
                                                  float* __restrict__ out_idxf,
                                                  int* __restrict__ counts) {
  const int n = blockIdx.x * 256 + threadIdx.x;
  float d0 = pd[n];
  int j0 = pj[n];
  for (int s = 1; s < NSPL; ++s) {
    const float d = pd[(size_t)s * Nrows + n];
    const int j = pj[(size_t)s * Nrows + n];
    if (d < d0 || (d == d0 && j < j0)) { d0 = d; j0 = j; }
  }
  idx_int[n] = j0;
  out_idxf[n] = (float)j0;
  atomicAdd(&counts[j0], 1);
}

// ---- gather zq (BCHW) + loss sum (unchanged, passed r1-r9) ----------------
__global__ __launch_bounds__(256) void vq_gather_loss(
    const float* __restrict__ z, const float* __restrict__ cb,
    const int* __restrict__ idx_int, float* __restrict__ outz,
    float* __restrict__ loss_sum) {
  const int g = blockIdx.x * 256 + threadIdx.x;
  const int hw4 = g & 255;
  const int c = (g >> 8) & 255;
  const int b = g >> 16;
  const int n = b * HWsz + hw4 * 4;
  const float4 zv = *(const float4*)(z + (size_t)g * 4);
  const int4 j4 = *(const int4*)(idx_int + n);
  float4 q;
  q.x = cb[(size_t)j4.x * Kdim + c];
  q.y = cb[(size_t)j4.y * Kdim + c];
  q.z = cb[(size_t)j4.z * Kdim + c];
  q.w = cb[(size_t)j4.w * Kdim + c];
  *(float4*)(outz + (size_t)g * 4) = q;
  float dx = q.x - zv.x, dy = q.y - zv.y, dz = q.z - zv.z, dw = q.w - zv.w;
  float s = dx * dx + dy * dy + dz * dz + dw * dw;
  for (int off = 32; off; off >>= 1) s += __shfl_down(s, off);
  __shared__ float ws4[4];
  if ((threadIdx.x & 63) == 0) ws4[threadIdx.x >> 6] = s;
  __syncthreads();
  if (threadIdx.x == 0) atomicAdd(loss_sum, (ws4[0] + ws4[1]) + (ws4[2] + ws4[3]));
}

// ---- scalars (unchanged) --------------------------------------------------
__global__ __launch_bounds__(256) void vq_final(const int* __restrict__ counts,
                                                const float* __restrict__ loss_sum,
                                                float* __restrict__ out_sc) {
  float h = 0.f;
  for (int i = threadIdx.x; i < NE; i += 256) {
    float p = (float)counts[i] * (1.0f / 16384.0f);
    h += p * logf(p + 1e-10f);
  }
  for (int off = 32; off; off >>= 1) h += __shfl_down(h, off);
  __shared__ float hs[4];
  if ((threadIdx.x & 63) == 0) hs[threadIdx.x >> 6] = h;
  __syncthreads();
  if (threadIdx.x == 0) {
    float H = (hs[0] + hs[1]) + (hs[2] + hs[3]);
    float m = loss_sum[0] * (1.0f / 4194304.0f);
    out_sc[0] = m + BETAF * m;
    out_sc[1] = expf(-H);
  }
}

extern "C" void kernel_launch(void* const* d_in, const int* in_sizes, int n_in,
                              void* d_out, int out_size, void* d_ws, size_t ws_size,
                              hipStream_t stream) {
  const float* z = (const float*)d_in[0];
  const float* cb = (const float*)d_in[1];
  float* out = (float*)d_out;
  float* out_zq = out;                     // 4194304
  float* out_sc = out + 4194304;           // loss, perplexity
  float* out_idx = out + 4194306;          // 16384 idx as float

  char* wp = (char*)d_ws;
  u16* Cf = (u16*)wp;           wp += (size_t)NE * Kdim * 2 * 3;
  u16* Zf = (u16*)wp;           wp += (size_t)Nrows * Kdim * 2 * 3;
  float* cc = (float*)wp;       wp += (size_t)NE * 4;
  float* zz = (float*)wp;       wp += (size_t)Nrows * 4;
  float* pd = (float*)wp;       wp += (size_t)NSPL * Nrows * 4;
  int* pj = (int*)wp;           wp += (size_t)NSPL * Nrows * 4;
  int* idx_int = (int*)wp;      wp += (size_t)Nrows * 4;
  int* counts = (int*)wp;       wp += (size_t)NE * 4;
  float* loss_sum = (float*)wp; wp += 64;

  hipMemsetAsync(counts, 0, (size_t)NE * 4, stream);
  hipMemsetAsync(loss_sum, 0, 4, stream);

  cc_kernel<<<NE / 4, 256, 0, stream>>>(cb, cc);
  conv_cb<<<NE * 16 / 256, 256, 0, stream>>>(cb, Cf);
  conv_z<<<Nrows / 64, 256, 0, stream>>>(z, Zf, zz);
  vq_gemm<<<512, 256, 0, stream>>>(Cf, Zf, cc, zz, pd, pj);
  vq_combine<<<Nrows / 256, 256, 0, stream>>>(pd, pj, idx_int, out_idx, counts);
  vq_gather_loss<<<4096, 256, 0, stream>>>(z, cb, idx_int, out_zq, loss_sum);
  vq_final<<<1, 256, 0, stream>>>(counts, loss_sum, out_sc);
}

// Round 5
// 428.681 us; speedup vs baseline: 1.1170x; 1.1170x over previous
//
#include <hip/hip_runtime.h>
#include <math.h>

#define Nrows 16384          // B*H*W
#define NE 8192
#define Kdim 256
#define HWsz 1024
#define NSPL 4               // code-group splits (cg)
#define BETAF 0.25f
#define NLOSSBLK 4096        // gather_loss grid (per-block loss partials)

typedef __attribute__((ext_vector_type(8))) short bf16x8;
typedef __attribute__((ext_vector_type(16))) float f32x16;
typedef unsigned short u16;

__device__ inline u16 bf16_rne(float x) {
  unsigned int u = __float_as_uint(x);
  return (u16)((u + 0x7FFFu + ((u >> 16) & 1u)) >> 16);
}
__device__ inline float bf16_tof(u16 h) {
  return __uint_as_float(((unsigned int)h) << 16);
}
__device__ inline void gll16(const void* g, void* l) {
  __builtin_amdgcn_global_load_lds(
      (const __attribute__((address_space(1))) unsigned int*)g,
      (__attribute__((address_space(3))) unsigned int*)l, 16, 0, 0);
}

// ---- cc[j] = sum_k codebook[j][k]^2 (bit-identical to r1-r10) -------------
__global__ __launch_bounds__(256) void cc_kernel(const float* __restrict__ cb,
                                                 float* __restrict__ cc) {
  int wave = threadIdx.x >> 6;
  int lane = threadIdx.x & 63;
  int row = blockIdx.x * 4 + wave;
  const float4 v = *(const float4*)(cb + (size_t)row * Kdim + lane * 4);
  float s = v.x * v.x + v.y * v.y + v.z * v.z + v.w * v.w;
  for (int off = 32; off; off >>= 1) s += __shfl_down(s, off);
  if (lane == 0) cc[row] = s;
}

// ---- codebook -> frag-order bf16 splits Cf (unchanged r4-r10) -------------
// Group (j32, arr, k16) of 512 u16 at ((j32*3+arr)*16 + k16)*512;
// within group: (khalf*32 + j%32)*8 + i.
__global__ __launch_bounds__(256) void conv_cb(const float* __restrict__ cb,
                                               u16* __restrict__ Cf) {
  const int g = blockIdx.x * 256 + threadIdx.x;   // 0 .. 8192*16-1
  const int j = g >> 4, k16 = g & 15;
  const float* src = cb + (size_t)j * Kdim + k16 * 16;
  float f[16];
#pragma unroll
  for (int q = 0; q < 4; ++q) {
    const float4 v = ((const float4*)src)[q];
    f[q * 4 + 0] = v.x; f[q * 4 + 1] = v.y; f[q * 4 + 2] = v.z; f[q * 4 + 3] = v.w;
  }
  u16 h[3][16];
#pragma unroll
  for (int i = 0; i < 16; ++i) {
    const u16 q0 = bf16_rne(f[i]);
    const float r1 = f[i] - bf16_tof(q0);
    const u16 q1 = bf16_rne(r1);
    const float r2 = r1 - bf16_tof(q1);
    h[0][i] = q0; h[1][i] = q1; h[2][i] = bf16_rne(r2);
  }
  const int j32 = j >> 5, li = j & 31;
#pragma unroll
  for (int arr = 0; arr < 3; ++arr) {
#pragma unroll
    for (int kh = 0; kh < 2; ++kh) {
      const size_t off = ((size_t)(j32 * 3 + arr) * 16 + k16) * 512 + (kh * 32 + li) * 8;
      *(int4*)(Cf + off) = *(int4*)&h[arr][kh * 8];
    }
  }
}

// ---- z (B,C,H,W) -> frag-order bf16 splits Zf + zz (unchanged r4-r10) -----
__global__ __launch_bounds__(256) void conv_z(const float* __restrict__ z,
                                              u16* __restrict__ Zf,
                                              float* __restrict__ zz) {
  __shared__ float tile[64][68];
  const int t = threadIdx.x;
  const int bid = blockIdx.x;
  const int n0 = bid * 64;
  const int b = bid >> 4;
  const int hw0 = (bid & 15) << 6;
  const float* zb = z + (size_t)b * (Kdim * HWsz) + hw0;
  float zzacc = 0.f;
  const int rr = t >> 2;
  const int kq = (t & 3) * 16;
  for (int kc = 0; kc < 4; ++kc) {
#pragma unroll
    for (int i = 0; i < 16; ++i) {
      const int idx = i * 256 + t;
      const int k = idx >> 6, r = idx & 63;
      tile[r][k] = zb[(size_t)(kc * 64 + k) * HWsz + r];
    }
    __syncthreads();
    if (t < 64) {
      for (int k = 0; k < 64; ++k) {
        const float a = tile[t][k];
        zzacc = fmaf(a, a, zzacc);
      }
    }
    u16 h[3][16];
#pragma unroll
    for (int i = 0; i < 16; ++i) {
      const float fv = tile[rr][kq + i];
      const u16 q0 = bf16_rne(fv);
      const float r1 = fv - bf16_tof(q0);
      const u16 q1 = bf16_rne(r1);
      const float r2 = r1 - bf16_tof(q1);
      h[0][i] = q0; h[1][i] = q1; h[2][i] = bf16_rne(r2);
    }
    const int k16 = kc * 4 + (t & 3);
    const int n32 = bid * 2 + (rr >> 5), li = rr & 31;
#pragma unroll
    for (int arr = 0; arr < 3; ++arr) {
#pragma unroll
      for (int kh = 0; kh < 2; ++kh) {
        const size_t off = ((size_t)(n32 * 3 + arr) * 16 + k16) * 512 + (kh * 32 + li) * 8;
        *(int4*)(Zf + off) = *(int4*)&h[arr][kh * 8];
      }
    }
    __syncthreads();
  }
  if (t < 64) zz[n0 + t] = zzacc;
}

// ---- main GEMM+argmin: EXACT r9 (3-slot rotation, stage lag 2, counted ----
// vmcnt(6), raw s_barrier, 24 KB chunks, 4 barriers/group). r10's setprio
// was neutral-to-negative (320->325 us, MfmaUtil 63.6->62.5) -> reverted.
// MFMA order per accumulator unchanged -> bit-identical output.
// LDS 3x24KB + 8KB ccs = 80 KB -> 2 blocks/CU.
__global__ __launch_bounds__(256, 2) void vq_gemm(
    const u16* __restrict__ Cf, const u16* __restrict__ Zf,
    const float* __restrict__ cc, const float* __restrict__ zz,
    float* __restrict__ pd, int* __restrict__ pj) {
  __shared__ __align__(16) u16 Al[3][12288];   // 3 x 24 KB rotating slots
  __shared__ float ccs[2048];                  // 80 KB total

  const int t = threadIdx.x;
  const int lane = t & 63;
  const int w = __builtin_amdgcn_readfirstlane(t >> 6);   // 0..3
  const int bid = blockIdx.x;
  const int cg = bid & 3;          // code slice (2048 codes), XCD-pinned
  const int rt = bid >> 2;         // row tile (128 rows)
  const int n32 = rt * 4 + w;      // this wave's 32-row group

#pragma unroll
  for (int i = 0; i < 8; ++i) ccs[i * 256 + t] = cc[cg * 2048 + i * 256 + t];

  const float zzv = zz[n32 * 32 + (lane & 31)];

  // B (z-rows) persistent: 16 kc x 3 limbs x bf16x8 = 192 VGPRs
  bf16x8 B[16][3];
#pragma unroll
  for (int kc = 0; kc < 16; ++kc)
#pragma unroll
    for (int arr = 0; arr < 3; ++arr)
      B[kc][arr] = *(const bf16x8*)(
          Zf + ((size_t)(n32 * 3 + arr) * 16 + kc) * 512 + lane * 8);

// stage chunk (gg, c_) of 64-code group gg into LDS slot sl: 24 cells of
// 1 KB, 6 per wave; dest = wave-uniform cell base + lane*16 (gll16 rule).
// Tail over-issue clamps gg to 0 (valid, L2-hot, lands in a dead slot).
#define STAGE(gg, c_, sl)                                                     \
  {                                                                           \
    const int ggc_ = (gg) < 32 ? (gg) : 0;                                    \
    _Pragma("unroll")                                                         \
    for (int i = 0; i < 6; ++i) {                                             \
      const int s = w * 6 + i;                                                \
      const int jx = s / 12, rem = s % 12;                                    \
      const int kc2 = rem / 3, arr = rem % 3;                                 \
      gll16(Cf + ((size_t)((cg * 64 + ggc_ * 2 + jx) * 3 + arr) * 16 +        \
                  ((c_) * 4 + kc2)) * 512 + lane * 8,                         \
            &Al[sl][((jx * 4 + kc2) * 3 + arr) * 512]);                       \
    }                                                                         \
  }

// per kc: 6 A-frag b128 reads feed 12 MFMAs; per-acc-element product order
// (a0b0,a0b1,a1b0,a1b1,a0b2,a2b0) ascending kc — bit-identical to r3-r10.
#define MF(af, bv, ac) ac = __builtin_amdgcn_mfma_f32_32x32x16_bf16(af, bv, ac, 0, 0, 0);
#define CHUNK(sl, c_)                                                         \
  _Pragma("unroll")                                                           \
  for (int kc2 = 0; kc2 < 4; ++kc2) {                                         \
    bf16x8 a0[3], a1[3];                                                      \
    _Pragma("unroll")                                                         \
    for (int arr = 0; arr < 3; ++arr) {                                       \
      a0[arr] = *(const bf16x8*)&Al[sl][(kc2 * 3 + arr) * 512 + lane * 8];    \
      a1[arr] = *(const bf16x8*)&Al[sl][((4 + kc2) * 3 + arr) * 512 + lane * 8]; \
    }                                                                         \
    MF(a0[0], B[(c_) * 4 + kc2][0], acc0) MF(a1[0], B[(c_) * 4 + kc2][0], acc1) \
    MF(a0[0], B[(c_) * 4 + kc2][1], acc0) MF(a1[0], B[(c_) * 4 + kc2][1], acc1) \
    MF(a0[1], B[(c_) * 4 + kc2][0], acc0) MF(a1[1], B[(c_) * 4 + kc2][0], acc1) \
    MF(a0[1], B[(c_) * 4 + kc2][1], acc0) MF(a1[1], B[(c_) * 4 + kc2][1], acc1) \
    MF(a0[0], B[(c_) * 4 + kc2][2], acc0) MF(a1[0], B[(c_) * 4 + kc2][2], acc1) \
    MF(a0[2], B[(c_) * 4 + kc2][0], acc0) MF(a1[2], B[(c_) * 4 + kc2][0], acc1) \
  }

// counted wait + raw barrier: certifies the chunk about to be read (all
// waves), never drains the two younger in-flight stages. sched_barrier(0)
// fences stop compile-time motion of ds_reads/MFMAs across it (rule #18).
#define WTB()                                                                 \
  __builtin_amdgcn_sched_barrier(0);                                          \
  asm volatile("s_waitcnt vmcnt(6)" ::: "memory");                            \
  __builtin_amdgcn_s_barrier();                                               \
  __builtin_amdgcn_sched_barrier(0);

#define ROT() { sl = (sl == 2) ? 0 : sl + 1; s2 = (s2 == 2) ? 0 : s2 + 1; }

  // prologue: stage phases 0 and 1 into slots 0 and 1
  STAGE(0, 0, 0)
  STAGE(0, 1, 1)
  // publish ccs ds_writes before the first raw barrier (raw s_barrier does
  // not drain lgkmcnt the way __syncthreads did)
  asm volatile("s_waitcnt lgkmcnt(0)" ::: "memory");
  __builtin_amdgcn_sched_barrier(0);

  float bd = INFINITY;
  int bj = 0;
  const f32x16 zero16 = {0,0,0,0,0,0,0,0,0,0,0,0,0,0,0,0};
  int sl = 0, s2 = 2;   // slot of current phase / of phase+2 (uniform)

  for (int g = 0; g < 32; ++g) {
    f32x16 acc0 = zero16, acc1 = zero16;
    // 4 phases per group; stage runs 2 phases ahead: (g,2),(g,3),(g+1,0),(g+1,1)
    WTB() STAGE(g, 2, s2)     CHUNK(sl, 0) ROT()
    WTB() STAGE(g, 3, s2)     CHUNK(sl, 1) ROT()
    WTB() STAGE(g + 1, 0, s2) CHUNK(sl, 2) ROT()
    WTB() STAGE(g + 1, 1, s2) CHUNK(sl, 3) ROT()

    // epilogue: d = (zz + cc) - 2*acc, ascending j (same expression r1-r10);
    // overlaps the two in-flight stages of the next group.
#pragma unroll
    for (int jx = 0; jx < 2; ++jx) {
      const f32x16& a = jx ? acc1 : acc0;
#pragma unroll
      for (int q = 0; q < 4; ++q) {
        const float4 c4 = *(const float4*)&ccs[g * 64 + jx * 32 + q * 8 + (lane >> 5) * 4];
        const float cv[4] = {c4.x, c4.y, c4.z, c4.w};
#pragma unroll
        for (int r = 0; r < 4; ++r) {
          const float d = (zzv + cv[r]) - 2.0f * a[q * 4 + r];
          const int j = cg * 2048 + g * 64 + jx * 32 + r + q * 8 + (lane >> 5) * 4;
          if (d < bd) { bd = d; bj = j; }
        }
      }
    }
  }
  // drain clamped tail stages: no gll16 LDS-write may be pending at
  // s_endpgm (LDS is reallocated to the next workgroup).
  asm volatile("s_waitcnt vmcnt(0)" ::: "memory");
#undef STAGE
#undef CHUNK
#undef MF
#undef WTB
#undef ROT

  // combine lane halves (same z-row, complementary code sub-columns)
  {
    const float od = __shfl_xor(bd, 32);
    const int oj = __shfl_xor(bj, 32);
    if (od < bd || (od == bd && oj < bj)) { bd = od; bj = oj; }
  }
  if (lane < 32) {
    const int n = n32 * 32 + lane;
    pd[(size_t)cg * Nrows + n] = bd;
    pj[(size_t)cg * Nrows + n] = bj;
  }
}

// ---- combine NSPL code-group partials -> idx, counts ----------------------
__global__ __launch_bounds__(256) void vq_combine(const float* __restrict__ pd,
                                                  const int* __restrict__ pj,
                                                  int* __restrict__ idx_int,
                                                  float* __restrict__ out_idxf,
                                                  int* __restrict__ counts) {
  const int n = blockIdx.x * 256 + threadIdx.x;
  float d0 = pd[n];
  int j0 = pj[n];
  for (int s = 1; s < NSPL; ++s) {
    const float d = pd[(size_t)s * Nrows + n];
    const int j = pj[(size_t)s * Nrows + n];
    if (d < d0 || (d == d0 && j < j0)) { d0 = d; j0 = j; }
  }
  idx_int[n] = j0;
  out_idxf[n] = (float)j0;
  atomicAdd(&counts[j0], 1);
}

// ---- gather zq (BCHW) + loss PARTIALS (r11: de-atomic) --------------------
// r1-r10 ended with 4096 same-address atomicAdd(loss_sum) — serialized L2
// RMWs, est. 50-90 us tail (Guideline 12 violation). Now each block writes
// loss_part[bid]; vq_final reduces the 4096 floats (16 KB read — free).
// Loss sum order changes, but atomic arrival order was already
// nondeterministic and passes -> within checker tolerance. Gather path
// (zq values, idx) untouched.
__global__ __launch_bounds__(256) void vq_gather_loss(
    const float* __restrict__ z, const float* __restrict__ cb,
    const int* __restrict__ idx_int, float* __restrict__ outz,
    float* __restrict__ loss_part) {
  const int g = blockIdx.x * 256 + threadIdx.x;
  const int hw4 = g & 255;
  const int c = (g >> 8) & 255;
  const int b = g >> 16;
  const int n = b * HWsz + hw4 * 4;
  const float4 zv = *(const float4*)(z + (size_t)g * 4);
  const int4 j4 = *(const int4*)(idx_int + n);
  float4 q;
  q.x = cb[(size_t)j4.x * Kdim + c];
  q.y = cb[(size_t)j4.y * Kdim + c];
  q.z = cb[(size_t)j4.z * Kdim + c];
  q.w = cb[(size_t)j4.w * Kdim + c];
  *(float4*)(outz + (size_t)g * 4) = q;
  float dx = q.x - zv.x, dy = q.y - zv.y, dz = q.z - zv.z, dw = q.w - zv.w;
  float s = dx * dx + dy * dy + dz * dz + dw * dw;
  for (int off = 32; off; off >>= 1) s += __shfl_down(s, off);
  __shared__ float ws4[4];
  if ((threadIdx.x & 63) == 0) ws4[threadIdx.x >> 6] = s;
  __syncthreads();
  if (threadIdx.x == 0)
    loss_part[blockIdx.x] = (ws4[0] + ws4[1]) + (ws4[2] + ws4[3]);
}

// ---- scalars: entropy + loss-partial reduction ----------------------------
__global__ __launch_bounds__(256) void vq_final(const int* __restrict__ counts,
                                                const float* __restrict__ loss_part,
                                                float* __restrict__ out_sc) {
  float h = 0.f;
  for (int i = threadIdx.x; i < NE; i += 256) {
    float p = (float)counts[i] * (1.0f / 16384.0f);
    h += p * logf(p + 1e-10f);
  }
  float ls = 0.f;
  for (int i = threadIdx.x; i < NLOSSBLK; i += 256) ls += loss_part[i];
  for (int off = 32; off; off >>= 1) {
    h += __shfl_down(h, off);
    ls += __shfl_down(ls, off);
  }
  __shared__ float hs[4], lss[4];
  if ((threadIdx.x & 63) == 0) {
    hs[threadIdx.x >> 6] = h;
    lss[threadIdx.x >> 6] = ls;
  }
  __syncthreads();
  if (threadIdx.x == 0) {
    float H = (hs[0] + hs[1]) + (hs[2] + hs[3]);
    float L = (lss[0] + lss[1]) + (lss[2] + lss[3]);
    float m = L * (1.0f / 4194304.0f);
    out_sc[0] = m + BETAF * m;
    out_sc[1] = expf(-H);
  }
}

extern "C" void kernel_launch(void* const* d_in, const int* in_sizes, int n_in,
                              void* d_out, int out_size, void* d_ws, size_t ws_size,
                              hipStream_t stream) {
  const float* z = (const float*)d_in[0];
  const float* cb = (const float*)d_in[1];
  float* out = (float*)d_out;
  float* out_zq = out;                     // 4194304
  float* out_sc = out + 4194304;           // loss, perplexity
  float* out_idx = out + 4194306;          // 16384 idx as float

  char* wp = (char*)d_ws;
  u16* Cf = (u16*)wp;           wp += (size_t)NE * Kdim * 2 * 3;
  u16* Zf = (u16*)wp;           wp += (size_t)Nrows * Kdim * 2 * 3;
  float* cc = (float*)wp;       wp += (size_t)NE * 4;
  float* zz = (float*)wp;       wp += (size_t)Nrows * 4;
  float* pd = (float*)wp;       wp += (size_t)NSPL * Nrows * 4;
  int* pj = (int*)wp;           wp += (size_t)NSPL * Nrows * 4;
  int* idx_int = (int*)wp;      wp += (size_t)Nrows * 4;
  int* counts = (int*)wp;       wp += (size_t)NE * 4;
  float* loss_part = (float*)wp; wp += (size_t)NLOSSBLK * 4;

  hipMemsetAsync(counts, 0, (size_t)NE * 4, stream);

  cc_kernel<<<NE / 4, 256, 0, stream>>>(cb, cc);
  conv_cb<<<NE * 16 / 256, 256, 0, stream>>>(cb, Cf);
  conv_z<<<Nrows / 64, 256, 0, stream>>>(z, Zf, zz);
  vq_gemm<<<512, 256, 0, stream>>>(Cf, Zf, cc, zz, pd, pj);
  vq_combine<<<Nrows / 256, 256, 0, stream>>>(pd, pj, idx_int, out_idx, counts);
  vq_gather_loss<<<NLOSSBLK, 256, 0, stream>>>(z, cb, idx_int, out_zq, loss_part);
  vq_final<<<1, 256, 0, stream>>>(counts, loss_part, out_sc);
}

// Round 8
// 420.162 us; speedup vs baseline: 1.1396x; 1.0203x over previous
//
#include <hip/hip_runtime.h>
#include <math.h>

#define Nrows 16384          // B*H*W
#define NE 8192
#define Kdim 256
#define HWsz 1024
#define NSPL 4               // code-group splits (cg)
#define BETAF 0.25f
#define NGATHBLK 1024        // gather grid: 256 row-tiles x 4 c-quarters

typedef __attribute__((ext_vector_type(8))) short bf16x8;
typedef __attribute__((ext_vector_type(16))) float f32x16;
typedef unsigned short u16;

__device__ inline u16 bf16_rne(float x) {
  unsigned int u = __float_as_uint(x);
  return (u16)((u + 0x7FFFu + ((u >> 16) & 1u)) >> 16);
}
__device__ inline float bf16_tof(u16 h) {
  return __uint_as_float(((unsigned int)h) << 16);
}
__device__ inline void gll16(const void* g, void* l) {
  __builtin_amdgcn_global_load_lds(
      (const __attribute__((address_space(1))) unsigned int*)g,
      (__attribute__((address_space(3))) unsigned int*)l, 16, 0, 0);
}

// ---- cc[j] = sum_k codebook[j][k]^2 (bit-identical to r1-r11) -------------
__global__ __launch_bounds__(256) void cc_kernel(const float* __restrict__ cb,
                                                 float* __restrict__ cc) {
  int wave = threadIdx.x >> 6;
  int lane = threadIdx.x & 63;
  int row = blockIdx.x * 4 + wave;
  const float4 v = *(const float4*)(cb + (size_t)row * Kdim + lane * 4);
  float s = v.x * v.x + v.y * v.y + v.z * v.z + v.w * v.w;
  for (int off = 32; off; off >>= 1) s += __shfl_down(s, off);
  if (lane == 0) cc[row] = s;
}

// ---- codebook -> frag-order bf16 splits Cf (unchanged r4-r11) -------------
// Group (j32, arr, k16) of 512 u16 at ((j32*3+arr)*16 + k16)*512;
// within group: (khalf*32 + j%32)*8 + i.
__global__ __launch_bounds__(256) void conv_cb(const float* __restrict__ cb,
                                               u16* __restrict__ Cf) {
  const int g = blockIdx.x * 256 + threadIdx.x;   // 0 .. 8192*16-1
  const int j = g >> 4, k16 = g & 15;
  const float* src = cb + (size_t)j * Kdim + k16 * 16;
  float f[16];
#pragma unroll
  for (int q = 0; q < 4; ++q) {
    const float4 v = ((const float4*)src)[q];
    f[q * 4 + 0] = v.x; f[q * 4 + 1] = v.y; f[q * 4 + 2] = v.z; f[q * 4 + 3] = v.w;
  }
  u16 h[3][16];
#pragma unroll
  for (int i = 0; i < 16; ++i) {
    const u16 q0 = bf16_rne(f[i]);
    const float r1 = f[i] - bf16_tof(q0);
    const u16 q1 = bf16_rne(r1);
    const float r2 = r1 - bf16_tof(q1);
    h[0][i] = q0; h[1][i] = q1; h[2][i] = bf16_rne(r2);
  }
  const int j32 = j >> 5, li = j & 31;
#pragma unroll
  for (int arr = 0; arr < 3; ++arr) {
#pragma unroll
    for (int kh = 0; kh < 2; ++kh) {
      const size_t off = ((size_t)(j32 * 3 + arr) * 16 + k16) * 512 + (kh * 32 + li) * 8;
      *(int4*)(Cf + off) = *(int4*)&h[arr][kh * 8];
    }
  }
}

// ---- z (B,C,H,W) -> frag-order bf16 splits Zf + zz (unchanged r4-r11) -----
__global__ __launch_bounds__(256) void conv_z(const float* __restrict__ z,
                                              u16* __restrict__ Zf,
                                              float* __restrict__ zz) {
  __shared__ float tile[64][68];
  const int t = threadIdx.x;
  const int bid = blockIdx.x;
  const int n0 = bid * 64;
  const int b = bid >> 4;
  const int hw0 = (bid & 15) << 6;
  const float* zb = z + (size_t)b * (Kdim * HWsz) + hw0;
  float zzacc = 0.f;
  const int rr = t >> 2;
  const int kq = (t & 3) * 16;
  for (int kc = 0; kc < 4; ++kc) {
#pragma unroll
    for (int i = 0; i < 16; ++i) {
      const int idx = i * 256 + t;
      const int k = idx >> 6, r = idx & 63;
      tile[r][k] = zb[(size_t)(kc * 64 + k) * HWsz + r];
    }
    __syncthreads();
    if (t < 64) {
      for (int k = 0; k < 64; ++k) {
        const float a = tile[t][k];
        zzacc = fmaf(a, a, zzacc);
      }
    }
    u16 h[3][16];
#pragma unroll
    for (int i = 0; i < 16; ++i) {
      const float fv = tile[rr][kq + i];
      const u16 q0 = bf16_rne(fv);
      const float r1 = fv - bf16_tof(q0);
      const u16 q1 = bf16_rne(r1);
      const float r2 = r1 - bf16_tof(q1);
      h[0][i] = q0; h[1][i] = q1; h[2][i] = bf16_rne(r2);
    }
    const int k16 = kc * 4 + (t & 3);
    const int n32 = bid * 2 + (rr >> 5), li = rr & 31;
#pragma unroll
    for (int arr = 0; arr < 3; ++arr) {
#pragma unroll
      for (int kh = 0; kh < 2; ++kh) {
        const size_t off = ((size_t)(n32 * 3 + arr) * 16 + k16) * 512 + (kh * 32 + li) * 8;
        *(int4*)(Zf + off) = *(int4*)&h[arr][kh * 8];
      }
    }
    __syncthreads();
  }
  if (t < 64) zz[n0 + t] = zzacc;
}

// ---- main GEMM+argmin: EXACT r9/r11 (3-slot rotation, stage lag 2, counted
// vmcnt(6), raw s_barrier, 24 KB chunks, 4 barriers/group). Measured 312-320
// us, MfmaUtil 64. MFMA order per accumulator unchanged -> bit-identical.
// LDS 3x24KB + 8KB ccs = 80 KB -> 2 blocks/CU.
__global__ __launch_bounds__(256, 2) void vq_gemm(
    const u16* __restrict__ Cf, const u16* __restrict__ Zf,
    const float* __restrict__ cc, const float* __restrict__ zz,
    float* __restrict__ pd, int* __restrict__ pj) {
  __shared__ __align__(16) u16 Al[3][12288];   // 3 x 24 KB rotating slots
  __shared__ float ccs[2048];                  // 80 KB total

  const int t = threadIdx.x;
  const int lane = t & 63;
  const int w = __builtin_amdgcn_readfirstlane(t >> 6);   // 0..3
  const int bid = blockIdx.x;
  const int cg = bid & 3;          // code slice (2048 codes), XCD-pinned
  const int rt = bid >> 2;         // row tile (128 rows)
  const int n32 = rt * 4 + w;      // this wave's 32-row group

#pragma unroll
  for (int i = 0; i < 8; ++i) ccs[i * 256 + t] = cc[cg * 2048 + i * 256 + t];

  const float zzv = zz[n32 * 32 + (lane & 31)];

  // B (z-rows) persistent: 16 kc x 3 limbs x bf16x8 = 192 VGPRs
  bf16x8 B[16][3];
#pragma unroll
  for (int kc = 0; kc < 16; ++kc)
#pragma unroll
    for (int arr = 0; arr < 3; ++arr)
      B[kc][arr] = *(const bf16x8*)(
          Zf + ((size_t)(n32 * 3 + arr) * 16 + kc) * 512 + lane * 8);

// stage chunk (gg, c_) of 64-code group gg into LDS slot sl: 24 cells of
// 1 KB, 6 per wave; dest = wave-uniform cell base + lane*16 (gll16 rule).
// Tail over-issue clamps gg to 0 (valid, L2-hot, lands in a dead slot).
#define STAGE(gg, c_, sl)                                                     \
  {                                                                           \
    const int ggc_ = (gg) < 32 ? (gg) : 0;                                    \
    _Pragma("unroll")                                                         \
    for (int i = 0; i < 6; ++i) {                                             \
      const int s = w * 6 + i;                                                \
      const int jx = s / 12, rem = s % 12;                                    \
      const int kc2 = rem / 3, arr = rem % 3;                                 \
      gll16(Cf + ((size_t)((cg * 64 + ggc_ * 2 + jx) * 3 + arr) * 16 +        \
                  ((c_) * 4 + kc2)) * 512 + lane * 8,                         \
            &Al[sl][((jx * 4 + kc2) * 3 + arr) * 512]);                       \
    }                                                                         \
  }

// per kc: 6 A-frag b128 reads feed 12 MFMAs; per-acc-element product order
// (a0b0,a0b1,a1b0,a1b1,a0b2,a2b0) ascending kc — bit-identical to r3-r11.
#define MF(af, bv, ac) ac = __builtin_amdgcn_mfma_f32_32x32x16_bf16(af, bv, ac, 0, 0, 0);
#define CHUNK(sl, c_)                                                         \
  _Pragma("unroll")                                                           \
  for (int kc2 = 0; kc2 < 4; ++kc2) {                                         \
    bf16x8 a0[3], a1[3];                                                      \
    _Pragma("unroll")                                                         \
    for (int arr = 0; arr < 3; ++arr) {                                       \
      a0[arr] = *(const bf16x8*)&Al[sl][(kc2 * 3 + arr) * 512 + lane * 8];    \
      a1[arr] = *(const bf16x8*)&Al[sl][((4 + kc2) * 3 + arr) * 512 + lane * 8]; \
    }                                                                         \
    MF(a0[0], B[(c_) * 4 + kc2][0], acc0) MF(a1[0], B[(c_) * 4 + kc2][0], acc1) \
    MF(a0[0], B[(c_) * 4 + kc2][1], acc0) MF(a1[0], B[(c_) * 4 + kc2][1], acc1) \
    MF(a0[1], B[(c_) * 4 + kc2][0], acc0) MF(a1[1], B[(c_) * 4 + kc2][0], acc1) \
    MF(a0[1], B[(c_) * 4 + kc2][1], acc0) MF(a1[1], B[(c_) * 4 + kc2][1], acc1) \
    MF(a0[0], B[(c_) * 4 + kc2][2], acc0) MF(a1[0], B[(c_) * 4 + kc2][2], acc1) \
    MF(a0[2], B[(c_) * 4 + kc2][0], acc0) MF(a1[2], B[(c_) * 4 + kc2][0], acc1) \
  }

// counted wait + raw barrier: certifies the chunk about to be read (all
// waves), never drains the two younger in-flight stages. sched_barrier(0)
// fences stop compile-time motion of ds_reads/MFMAs across it (rule #18).
#define WTB()                                                                 \
  __builtin_amdgcn_sched_barrier(0);                                          \
  asm volatile("s_waitcnt vmcnt(6)" ::: "memory");                            \
  __builtin_amdgcn_s_barrier();                                               \
  __builtin_amdgcn_sched_barrier(0);

#define ROT() { sl = (sl == 2) ? 0 : sl + 1; s2 = (s2 == 2) ? 0 : s2 + 1; }

  // prologue: stage phases 0 and 1 into slots 0 and 1
  STAGE(0, 0, 0)
  STAGE(0, 1, 1)
  // publish ccs ds_writes before the first raw barrier (raw s_barrier does
  // not drain lgkmcnt the way __syncthreads did)
  asm volatile("s_waitcnt lgkmcnt(0)" ::: "memory");
  __builtin_amdgcn_sched_barrier(0);

  float bd = INFINITY;
  int bj = 0;
  const f32x16 zero16 = {0,0,0,0,0,0,0,0,0,0,0,0,0,0,0,0};
  int sl = 0, s2 = 2;   // slot of current phase / of phase+2 (uniform)

  for (int g = 0; g < 32; ++g) {
    f32x16 acc0 = zero16, acc1 = zero16;
    // 4 phases per group; stage runs 2 phases ahead: (g,2),(g,3),(g+1,0),(g+1,1)
    WTB() STAGE(g, 2, s2)     CHUNK(sl, 0) ROT()
    WTB() STAGE(g, 3, s2)     CHUNK(sl, 1) ROT()
    WTB() STAGE(g + 1, 0, s2) CHUNK(sl, 2) ROT()
    WTB() STAGE(g + 1, 1, s2) CHUNK(sl, 3) ROT()

    // epilogue: d = (zz + cc) - 2*acc, ascending j (same expression r1-r11);
    // overlaps the two in-flight stages of the next group.
#pragma unroll
    for (int jx = 0; jx < 2; ++jx) {
      const f32x16& a = jx ? acc1 : acc0;
#pragma unroll
      for (int q = 0; q < 4; ++q) {
        const float4 c4 = *(const float4*)&ccs[g * 64 + jx * 32 + q * 8 + (lane >> 5) * 4];
        const float cv[4] = {c4.x, c4.y, c4.z, c4.w};
#pragma unroll
        for (int r = 0; r < 4; ++r) {
          const float d = (zzv + cv[r]) - 2.0f * a[q * 4 + r];
          const int j = cg * 2048 + g * 64 + jx * 32 + r + q * 8 + (lane >> 5) * 4;
          if (d < bd) { bd = d; bj = j; }
        }
      }
    }
  }
  // drain clamped tail stages: no gll16 LDS-write may be pending at
  // s_endpgm (LDS is reallocated to the next workgroup).
  asm volatile("s_waitcnt vmcnt(0)" ::: "memory");
#undef STAGE
#undef CHUNK
#undef MF
#undef WTB
#undef ROT

  // combine lane halves (same z-row, complementary code sub-columns)
  {
    const float od = __shfl_xor(bd, 32);
    const int oj = __shfl_xor(bj, 32);
    if (od < bd || (od == bd && oj < bj)) { bd = od; bj = oj; }
  }
  if (lane < 32) {
    const int n = n32 * 32 + lane;
    pd[(size_t)cg * Nrows + n] = bd;
    pj[(size_t)cg * Nrows + n] = bj;
  }
}

// ---- fused combine + gather zq + loss (r13: 1024-block, 17 KB LDS) --------
// Same theory as r12 (coalesce the 16.8M scattered 4B codebook reads via
// LDS staging + lane<->hw transpose), restructured: grid 1024 = 256 row-
// tiles x 4 c-quarters; 17 KB LDS/block -> 4 blocks/CU (vs r12-v1's 1) and
// no >64KB static LDS. All 4 cq blocks recompute the cheap 4-way argmin
// (identical comparison order -> bit-identical idx); only cq==0 publishes
// out_idx/counts. Stride-65 LDS rows: phase-3 read banks (lane+c)%32 =
// 2-way (free). Phase-3 z-read / zq-write: 64 consecutive floats per
// wave-instr. Loss fp32 sum order differs from r11 (checker already
// tolerant — absmax was unchanged when r11 changed the order); zq values
// are bit-exact copies.
__global__ __launch_bounds__(256) void vq_gather_loss(
    const float* __restrict__ z, const float* __restrict__ cb,
    const float* __restrict__ pd, const int* __restrict__ pj,
    float* __restrict__ outz, float* __restrict__ out_idxf,
    int* __restrict__ counts, float* __restrict__ loss_part) {
  __shared__ float cbl[64 * 65];    // 16.6 KB, stride 65
  __shared__ int jr[64];
  __shared__ float ws4[4];
  const int t = threadIdx.x;
  const int bid = blockIdx.x;       // 0..1023
  const int nt = bid >> 2;          // row tile 0..255
  const int cq = bid & 3;           // c-quarter 0..3
  const int b = nt >> 4;
  const int hw0 = (nt & 15) << 6;
  const int n0 = b * HWsz + hw0;

  // phase 1: combine NSPL partials (same expression/order as r11 vq_combine)
  if (t < 64) {
    const int n = n0 + t;
    float d0 = pd[n];
    int j0 = pj[n];
    for (int s = 1; s < NSPL; ++s) {
      const float d = pd[(size_t)s * Nrows + n];
      const int j = pj[(size_t)s * Nrows + n];
      if (d < d0 || (d == d0 && j < j0)) { d0 = d; j0 = j; }
    }
    jr[t] = j0;
    if (cq == 0) {
      out_idxf[n] = (float)j0;
      atomicAdd(&counts[j0], 1);
    }
  }
  __syncthreads();

  // phase 2: stage 64 rows x this block's 64-c slice; thread t covers row
  // t>>2, 16 contiguous floats at c-offset (t&3)*16 -> 64 B/thread, rows
  // wave-uniform per 4 lanes -> coalesced 256 B/row segments.
  {
    const int r = t >> 2;
    const int c0 = (t & 3) * 16;
    const int j = jr[r];
    const float* src = cb + (size_t)j * Kdim + cq * 64 + c0;
#pragma unroll
    for (int q = 0; q < 4; ++q) {
      const float4 v = ((const float4*)src)[q];
      float* dst = &cbl[r * 65 + c0 + q * 4];
      dst[0] = v.x; dst[1] = v.y; dst[2] = v.z; dst[3] = v.w;
    }
  }
  __syncthreads();

  const int w = t >> 6, lane = t & 63;

  // phase 3: lane<->hw; wave w covers c_local = w*16 .. w*16+15
  float ls = 0.f;
  for (int k = 0; k < 16; ++k) {
    const int cl = w * 16 + k;
    const int c = cq * 64 + cl;
    const float q = cbl[lane * 65 + cl];
    const size_t gidx = ((size_t)(b * Kdim + c)) * HWsz + hw0 + lane;
    const float zv = z[gidx];
    outz[gidx] = q;
    const float dd = q - zv;
    ls = fmaf(dd, dd, ls);
  }
  for (int off = 32; off; off >>= 1) ls += __shfl_down(ls, off);
  if (lane == 0) ws4[w] = ls;
  __syncthreads();
  if (t == 0) loss_part[bid] = (ws4[0] + ws4[1]) + (ws4[2] + ws4[3]);
}

// ---- scalars: entropy + loss-partial reduction ----------------------------
__global__ __launch_bounds__(256) void vq_final(const int* __restrict__ counts,
                                                const float* __restrict__ loss_part,
                                                float* __restrict__ out_sc) {
  float h = 0.f;
  for (int i = threadIdx.x; i < NE; i += 256) {
    float p = (float)counts[i] * (1.0f / 16384.0f);
    h += p * logf(p + 1e-10f);
  }
  float ls = 0.f;
  for (int i = threadIdx.x; i < NGATHBLK; i += 256) ls += loss_part[i];
  for (int off = 32; off; off >>= 1) {
    h += __shfl_down(h, off);
    ls += __shfl_down(ls, off);
  }
  __shared__ float hs[4], lss[4];
  if ((threadIdx.x & 63) == 0) {
    hs[threadIdx.x >> 6] = h;
    lss[threadIdx.x >> 6] = ls;
  }
  __syncthreads();
  if (threadIdx.x == 0) {
    float H = (hs[0] + hs[1]) + (hs[2] + hs[3]);
    float L = (lss[0] + lss[1]) + (lss[2] + lss[3]);
    float m = L * (1.0f / 4194304.0f);
    out_sc[0] = m + BETAF * m;
    out_sc[1] = expf(-H);
  }
}

extern "C" void kernel_launch(void* const* d_in, const int* in_sizes, int n_in,
                              void* d_out, int out_size, void* d_ws, size_t ws_size,
                              hipStream_t stream) {
  const float* z = (const float*)d_in[0];
  const float* cb = (const float*)d_in[1];
  float* out = (float*)d_out;
  float* out_zq = out;                     // 4194304
  float* out_sc = out + 4194304;           // loss, perplexity
  float* out_idx = out + 4194306;          // 16384 idx as float

  char* wp = (char*)d_ws;
  u16* Cf = (u16*)wp;           wp += (size_t)NE * Kdim * 2 * 3;
  u16* Zf = (u16*)wp;           wp += (size_t)Nrows * Kdim * 2 * 3;
  float* cc = (float*)wp;       wp += (size_t)NE * 4;
  float* zz = (float*)wp;       wp += (size_t)Nrows * 4;
  float* pd = (float*)wp;       wp += (size_t)NSPL * Nrows * 4;
  int* pj = (int*)wp;           wp += (size_t)NSPL * Nrows * 4;
  int* counts = (int*)wp;       wp += (size_t)NE * 4;
  float* loss_part = (float*)wp; wp += (size_t)NGATHBLK * 4;

  hipMemsetAsync(counts, 0, (size_t)NE * 4, stream);

  cc_kernel<<<NE / 4, 256, 0, stream>>>(cb, cc);
  conv_cb<<<NE * 16 / 256, 256, 0, stream>>>(cb, Cf);
  conv_z<<<Nrows / 64, 256, 0, stream>>>(z, Zf, zz);
  vq_gemm<<<512, 256, 0, stream>>>(Cf, Zf, cc, zz, pd, pj);
  vq_gather_loss<<<NGATHBLK, 256, 0, stream>>>(z, cb, pd, pj, out_zq, out_idx,
                                               counts, loss_part);
  vq_final<<<1, 256, 0, stream>>>(counts, loss_part, out_sc);
}